// Round 2
// baseline (601.907 us; speedup 1.0000x reference)
//
#include <hip/hip_runtime.h>

#define NEG_INF -1000000000.0f
#define WINDOW 256

typedef float float4v __attribute__((ext_vector_type(4)));

// Sliding-window causal mask fill:
// keep iff (row - WINDOW) <= col <= row, else write NEG_INF.
// Memory-bound: skip global reads for fully-masked vec4s (write-only there).
__global__ void swa_mask_kernel(const float* __restrict__ in,
                                const int* __restrict__ seq_len_p,
                                float* __restrict__ out,
                                unsigned n_vec4) {
    const int T = *seq_len_p;      // broadcast scalar (L2-cached)
    const unsigned T4 = (unsigned)T >> 2;  // vec4 columns per row (T % 4 == 0)

    unsigned idx = blockIdx.x * blockDim.x + threadIdx.x;
    const unsigned stride = gridDim.x * blockDim.x;

    const float4v neg = {NEG_INF, NEG_INF, NEG_INF, NEG_INF};

    for (unsigned v = idx; v < n_vec4; v += stride) {
        unsigned rowg = v / T4;                    // global row over B*H*T
        int col = (int)((v - rowg * T4) << 2);     // first column of this vec4
        int row = (int)(rowg % (unsigned)T);       // row within the T x T tile
        int lo = row - WINDOW;                     // kept band: [lo, row]

        float4v r = neg;
        // Only touch HBM if any of the 4 elements is inside the band.
        if (col + 3 >= lo && col <= row) {
            float4v x = *((const float4v*)in + v);
            #pragma unroll
            for (int j = 0; j < 4; ++j) {
                int c = col + j;
                r[j] = (c >= lo && c <= row) ? x[j] : NEG_INF;
            }
        }
        *((float4v*)out + v) = r;
    }
}

extern "C" void kernel_launch(void* const* d_in, const int* in_sizes, int n_in,
                              void* d_out, int out_size, void* d_ws, size_t ws_size,
                              hipStream_t stream) {
    const float* in = (const float*)d_in[0];
    const int* seq_len_p = (const int*)d_in[1];
    float* out = (float*)d_out;

    unsigned n_vec4 = (unsigned)out_size >> 2;   // out_size divisible by 4 (T multiple of 4)

    const int block = 256;
    // Memory-bound: ~8 blocks/CU x 256 CUs, grid-stride the rest (G11).
    int grid = (int)((n_vec4 + block - 1) / block);
    if (grid > 2048) grid = 2048;

    swa_mask_kernel<<<grid, block, 0, stream>>>(in, seq_len_p, out, n_vec4);
}

// Round 17
// 601.532 us; speedup vs baseline: 1.0006x; 1.0006x over previous
//
#include <hip/hip_runtime.h>

#define NEG_INF -1000000000.0f
#define WINDOW 256

typedef float float4v __attribute__((ext_vector_type(4)));

// Sliding-window causal mask fill:
// keep iff (row - WINDOW) <= col <= row, else write NEG_INF.
// Memory-bound: skip global reads for fully-masked vec4s (write-only there).
// Round-3 change: power-of-two fast path removes per-iteration u32 div/mod
// (~25 VALU instrs -> ~4) when T is a power of two (T=2048 here).
__global__ __launch_bounds__(256) void swa_mask_kernel(
    const float* __restrict__ in,
    const int* __restrict__ seq_len_p,
    float* __restrict__ out,
    unsigned n_vec4) {
    const unsigned T = (unsigned)*seq_len_p;   // broadcast scalar (L2-cached)
    const unsigned T4 = T >> 2;                // vec4 columns per row (T % 4 == 0)
    const bool pow2 = (T4 & (T4 - 1)) == 0;    // T pow2 <=> T4 pow2 (T = 4*T4)
    const unsigned sh = 31 - __clz(T4 | 1);    // log2(T4) when pow2

    unsigned idx = blockIdx.x * blockDim.x + threadIdx.x;
    const unsigned stride = gridDim.x * blockDim.x;

    const float4v neg = {NEG_INF, NEG_INF, NEG_INF, NEG_INF};

    for (unsigned v = idx; v < n_vec4; v += stride) {
        unsigned rowg = pow2 ? (v >> sh) : (v / T4);   // global row over B*H*T
        int col = (int)((v - rowg * T4) << 2);         // first column of this vec4
        int row = (int)(pow2 ? (rowg & (T - 1)) : (rowg % T)); // row in T x T tile
        int lo = row - WINDOW;                          // kept band: [lo, row]

        float4v r = neg;
        // Only touch HBM if any of the 4 elements is inside the band.
        if (col + 3 >= lo && col <= row) {
            float4v x = *((const float4v*)in + v);
            #pragma unroll
            for (int j = 0; j < 4; ++j) {
                int c = col + j;
                r[j] = (c >= lo && c <= row) ? x[j] : NEG_INF;
            }
        }
        *((float4v*)out + v) = r;
    }
}

extern "C" void kernel_launch(void* const* d_in, const int* in_sizes, int n_in,
                              void* d_out, int out_size, void* d_ws, size_t ws_size,
                              hipStream_t stream) {
    const float* in = (const float*)d_in[0];
    const int* seq_len_p = (const int*)d_in[1];
    float* out = (float*)d_out;

    unsigned n_vec4 = (unsigned)out_size >> 2;   // out_size divisible by 4 (T multiple of 4)

    const int block = 256;
    // Memory-bound: ~8 blocks/CU x 256 CUs, grid-stride the rest (G11).
    int grid = (int)((n_vec4 + block - 1) / block);
    if (grid > 2048) grid = 2048;

    swa_mask_kernel<<<grid, block, 0, stream>>>(in, seq_len_p, out, n_vec4);
}